// Round 4
// baseline (82.871 us; speedup 1.0000x reference)
//
#include <hip/hip_runtime.h>
#include <math.h>

#define NJ 7
#define DTF 0.01f
#define GRAVF 9.81f
#define MIX(i,j) ((i)*((i)+1)/2 + (j))
#define MPAD 29   // 28 lower-tri floats padded to 29
#define CW 44     // const floats per joint in d_ws (16B-aligned stride)

// Per-joint constant block at cst + j*CW:
// [0:9)  Rt        (R_tree, row-major)
// [9:18) KR = skew(a) @ Rt
// [18:27) AR = (a a^T) @ Rt        => E(q) = c*Rt - s*KR + (1-c)*AR
// [27:30) a   [30:33) p
// [33:39) SA = (A00,A01,A02,A11,A12,A22) of spatial-inertia top-left block
// [39:42) h (first moment)   [42] m

__device__ __forceinline__ void cross3(const float* a, const float* b, float* o){
    o[0] = a[1]*b[2] - a[2]*b[1];
    o[1] = a[2]*b[0] - a[0]*b[2];
    o[2] = a[0]*b[1] - a[1]*b[0];
}
__device__ __forceinline__ void mv3(const float* E, const float* x, float* y){
    y[0] = E[0]*x[0] + E[1]*x[1] + E[2]*x[2];
    y[1] = E[3]*x[0] + E[4]*x[1] + E[5]*x[2];
    y[2] = E[6]*x[0] + E[7]*x[1] + E[8]*x[2];
}
__device__ __forceinline__ void mtv3(const float* E, const float* x, float* y){
    y[0] = E[0]*x[0] + E[3]*x[1] + E[6]*x[2];
    y[1] = E[1]*x[0] + E[4]*x[1] + E[7]*x[2];
    y[2] = E[2]*x[0] + E[5]*x[1] + E[8]*x[2];
}
__device__ __forceinline__ void symv(const float* S, const float* x, float* y){
    y[0] = S[0]*x[0] + S[1]*x[1] + S[2]*x[2];
    y[1] = S[1]*x[0] + S[3]*x[1] + S[4]*x[2];
    y[2] = S[2]*x[0] + S[4]*x[1] + S[5]*x[2];
}
__device__ __forceinline__ void mm3(const float* A, const float* B, float* o){
#pragma unroll
    for (int r = 0; r < 3; r++)
#pragma unroll
        for (int c = 0; c < 3; c++)
            o[r*3+c] = A[r*3]*B[c] + A[r*3+1]*B[3+c] + A[r*3+2]*B[6+c];
}
__device__ __forceinline__ void congr(const float* E, const float* X, float* o){
    float t[9];
#pragma unroll
    for (int r = 0; r < 3; r++)
#pragma unroll
        for (int c = 0; c < 3; c++)
            t[r*3+c] = E[r]*X[c] + E[3+r]*X[3+c] + E[6+r]*X[6+c];
    mm3(t, E, o);
}
// E = c*Rt - s*KR + (1-c)*AR  (27 FMA-class ops, 1 SGPR const per op)
__device__ __forceinline__ void makeE(const float* __restrict__ cb, float s, float c, float* E){
    float omc = 1.0f - c;
#pragma unroll
    for (int k = 0; k < 9; k++) E[k] = c*cb[k] - s*cb[9+k] + omc*cb[18+k];
}

__global__ void panda_prep(const float* __restrict__ g_ax, const float* __restrict__ g_Rt,
                           const float* __restrict__ g_pt, const float* __restrict__ g_I,
                           float* __restrict__ cst)
{
    int i = threadIdx.x;
    if (i >= NJ) return;
    float a0 = g_ax[i*3], a1 = g_ax[i*3+1], a2 = g_ax[i*3+2];
    const float* R = g_Rt + i*9;
    float* o = cst + i*CW;
#pragma unroll
    for (int k = 0; k < 9; k++) o[k] = R[k];
#pragma unroll
    for (int c = 0; c < 3; c++){
        o[9+c]  = -a2*R[3+c] + a1*R[6+c];   // (K@Rt) row 0
        o[12+c] =  a2*R[c]   - a0*R[6+c];   // row 1
        o[15+c] = -a1*R[c]   + a0*R[3+c];   // row 2
        float d =  a0*R[c] + a1*R[3+c] + a2*R[6+c];
        o[18+c] = a0*d; o[21+c] = a1*d; o[24+c] = a2*d;
    }
    o[27]=a0; o[28]=a1; o[29]=a2;
    o[30]=g_pt[i*3]; o[31]=g_pt[i*3+1]; o[32]=g_pt[i*3+2];
    const float* I6 = g_I + i*36;
    o[33]=I6[0];  o[34]=I6[1];  o[35]=I6[2];   // A00 A01 A02
    o[36]=I6[7];  o[37]=I6[8];  o[38]=I6[14];  // A11 A12 A22
    o[39]=I6[16]; o[40]=I6[5];  o[41]=I6[9];   // h = (B[2][1], B[0][2], B[1][0])
    o[42]=I6[21];                               // m
}

// Block = 128 threads = 2 waves on the SAME 64 batch elements.
// Wave 0: RNEA bias -> rhs, then Cholesky solve + output. Wave 1: CRBA -> LDS.
__global__ __launch_bounds__(128)
void panda_step(const float* __restrict__ x, const float* __restrict__ u,
                const float* __restrict__ cst, float* __restrict__ out, int B)
{
    __shared__ float s_M[64*MPAD];

    const int role = threadIdx.x >> 6;      // wave-uniform
    const int lane = threadIdx.x & 63;
    const int e    = blockIdx.x*64 + lane;
    const bool act = (e < B);

    const float QL[NJ] = {-2.9671f,-1.8326f,-2.9671f,-3.1416f,-2.9671f,-0.0873f,-2.9671f};
    const float QU[NJ] = { 2.9671f, 1.8326f, 2.9671f, 0.0f,    2.9671f, 3.8223f, 2.9671f};

    float q[NJ], qd[NJ], sn[NJ], cs[NJ];
    if (act){
        float xl[14];
        const float2* x2 = (const float2*)(x + e*14);
#pragma unroll
        for (int i = 0; i < 7; i++){ float2 v = x2[i]; xl[2*i] = v.x; xl[2*i+1] = v.y; }
#pragma unroll
        for (int i = 0; i < NJ; i++){
            q[i]  = fminf(fmaxf(xl[i], QL[i]), QU[i]);
            qd[i] = xl[NJ + i];
            __sincosf(q[i], &sn[i], &cs[i]);
        }
    }

    float rhs[NJ];

    if (act && role == 1){
        // =================== CRBA: mass matrix ===================
        const float* cb6 = cst + 6*CW;
        float SA[6] = {cb6[33],cb6[34],cb6[35],cb6[36],cb6[37],cb6[38]};
        float hc[3] = {cb6[39],cb6[40],cb6[41]};
        float mc = cb6[42];
        float Fk[NJ][6];
        float Mx[28];
#pragma unroll
        for (int i = NJ-1; i >= 0; i--){
            const float* cb = cst + i*CW;
            const float* a = cb+27;
            const float* p = cb+30;
            // F_i = Ic @ S_i = [A a ; a x h]
            symv(SA, a, &Fk[i][0]);
            Fk[i][3] = a[1]*hc[2] - a[2]*hc[1];
            Fk[i][4] = a[2]*hc[0] - a[0]*hc[2];
            Fk[i][5] = a[0]*hc[1] - a[1]*hc[0];
#pragma unroll
            for (int k = i; k < NJ; k++)
                Mx[MIX(k,i)] = a[0]*Fk[k][0] + a[1]*Fk[k][1] + a[2]*Fk[k][2];
            if (i > 0){
                float E[9]; makeE(cb, sn[i], cs[i], E);
                float Af[9] = {SA[0],SA[1],SA[2], SA[1],SA[3],SA[4], SA[2],SA[4],SA[5]};
                float Ap[9]; congr(E, Af, Ap);
                float hr[3]; mtv3(E, hc, hr);
                float hpd = hr[0]*p[0]+hr[1]*p[1]+hr[2]*p[2];
                float ppd = p[0]*p[0]+p[1]*p[1]+p[2]*p[2];
                float dga = 2.0f*hpd + mc*ppd;
                const float* cn = cst + (i-1)*CW;
                SA[0] = Ap[0] - 2.0f*p[0]*hr[0] - mc*p[0]*p[0] + dga + cn[33];
                SA[1] = Ap[1] - p[0]*hr[1] - hr[0]*p[1] - mc*p[0]*p[1] + cn[34];
                SA[2] = Ap[2] - p[0]*hr[2] - hr[0]*p[2] - mc*p[0]*p[2] + cn[35];
                SA[3] = Ap[4] - 2.0f*p[1]*hr[1] - mc*p[1]*p[1] + dga + cn[36];
                SA[4] = Ap[5] - p[1]*hr[2] - hr[1]*p[2] - mc*p[1]*p[2] + cn[37];
                SA[5] = Ap[8] - 2.0f*p[2]*hr[2] - mc*p[2]*p[2] + dga + cn[38];
                hc[0] = hr[0] + mc*p[0] + cn[39];
                hc[1] = hr[1] + mc*p[1] + cn[40];
                hc[2] = hr[2] + mc*p[2] + cn[41];
                mc += cn[42];
#pragma unroll
                for (int k = i; k < NJ; k++){
                    float tm[3], tf[3], cp[3];
                    mtv3(E, &Fk[k][0], tm); mtv3(E, &Fk[k][3], tf);
                    cross3(p, tf, cp);
                    Fk[k][0]=tm[0]+cp[0]; Fk[k][1]=tm[1]+cp[1]; Fk[k][2]=tm[2]+cp[2];
                    Fk[k][3]=tf[0];       Fk[k][4]=tf[1];       Fk[k][5]=tf[2];
                }
            }
        }
#pragma unroll
        for (int j = 0; j < 28; j++) s_M[lane*MPAD + j] = Mx[j];
    }
    else if (act){
        // =================== RNEA: bias forces ===================
#pragma unroll
        for (int i = 0; i < NJ; i++) rhs[i] = u[e*NJ + i];
        float FF[NJ][6];
        float w[3]  = {0.f,0.f,0.f}, vl[3] = {0.f,0.f,0.f};
        float aw[3] = {0.f,0.f,0.f}, av[3] = {0.f,0.f,GRAVF};
#pragma unroll
        for (int i = 0; i < NJ; i++){
            const float* cb = cst + i*CW;
            const float* a = cb+27;
            const float* p = cb+30;
            float E[9]; makeE(cb, sn[i], cs[i], E);
            float qdi = qd[i];
            float tw[3]; mv3(E, w, tw);
            float nw[3] = { tw[0]+a[0]*qdi, tw[1]+a[1]*qdi, tw[2]+a[2]*qdi };
            float cwp[3]; cross3(w, p, cwp);
            float t1[3] = { vl[0]+cwp[0], vl[1]+cwp[1], vl[2]+cwp[2] };
            float nvl[3]; mv3(E, t1, nvl);
            float taw[3]; mv3(E, aw, taw);
            float cna[3]; cross3(nw, a, cna);
            float naw[3] = { taw[0]+qdi*cna[0], taw[1]+qdi*cna[1], taw[2]+qdi*cna[2] };
            float cap[3]; cross3(aw, p, cap);
            float t2[3] = { av[0]+cap[0], av[1]+cap[1], av[2]+cap[2] };
            float tav[3]; mv3(E, t2, tav);
            float cva[3]; cross3(nvl, a, cva);
            float nav[3] = { tav[0]+qdi*cva[0], tav[1]+qdi*cva[1], tav[2]+qdi*cva[2] };
            const float* SAi = cb+33;
            const float* hi  = cb+39;
            float mi = cb[42];
            float Ivt[3], Iat[3], hxv[3], hxa[3];
            symv(SAi, nw, Ivt);  cross3(hi, nvl, hxv);
            symv(SAi, naw, Iat); cross3(hi, nav, hxa);
#pragma unroll
            for (int k = 0; k < 3; k++){ Ivt[k] += hxv[k]; Iat[k] += hxa[k]; }
            float hxw[3], hxaw[3];
            cross3(hi, nw, hxw); cross3(hi, naw, hxaw);
            float Ivb[3] = { mi*nvl[0]-hxw[0], mi*nvl[1]-hxw[1], mi*nvl[2]-hxw[2] };
            float Iab[3] = { mi*nav[0]-hxaw[0], mi*nav[1]-hxaw[1], mi*nav[2]-hxaw[2] };
            float c1[3], c2[3], c3[3];
            cross3(nw, Ivt, c1); cross3(nvl, Ivb, c2); cross3(nw, Ivb, c3);
            FF[i][0] = Iat[0]+c1[0]+c2[0];
            FF[i][1] = Iat[1]+c1[1]+c2[1];
            FF[i][2] = Iat[2]+c1[2]+c2[2];
            FF[i][3] = Iab[0]+c3[0];
            FF[i][4] = Iab[1]+c3[1];
            FF[i][5] = Iab[2]+c3[2];
#pragma unroll
            for (int k = 0; k < 3; k++){ w[k]=nw[k]; vl[k]=nvl[k]; aw[k]=naw[k]; av[k]=nav[k]; }
        }
#pragma unroll
        for (int i = NJ-1; i >= 0; i--){
            const float* cb = cst + i*CW;
            const float* a = cb+27;
            rhs[i] -= a[0]*FF[i][0] + a[1]*FF[i][1] + a[2]*FF[i][2];
            if (i > 0){
                const float* p = cb+30;
                float E[9]; makeE(cb, sn[i], cs[i], E);
                float tm[3], tf[3], cp[3];
                mtv3(E, &FF[i][0], tm); mtv3(E, &FF[i][3], tf);
                cross3(p, tf, cp);
                FF[i-1][0]+=tm[0]+cp[0]; FF[i-1][1]+=tm[1]+cp[1]; FF[i-1][2]+=tm[2]+cp[2];
                FF[i-1][3]+=tf[0];       FF[i-1][4]+=tf[1];       FF[i-1][5]+=tf[2];
            }
        }
    }

    __syncthreads();

    if (act && role == 0){
        float Mx[28];
#pragma unroll
        for (int j = 0; j < 28; j++) Mx[j] = s_M[lane*MPAD + j];
#pragma unroll
        for (int i = 0; i < NJ; i++) Mx[MIX(i,i)] += 1e-8f;

#pragma unroll
        for (int k = 0; k < NJ; k++){
            float d = Mx[MIX(k,k)];
#pragma unroll
            for (int j = 0; j < NJ; j++) if (j < k) d -= Mx[MIX(k,j)]*Mx[MIX(k,j)];
            float linv = __builtin_amdgcn_rsqf(d);
            Mx[MIX(k,k)] = linv;
#pragma unroll
            for (int i = k+1; i < NJ; i++){
                float s2 = Mx[MIX(i,k)];
#pragma unroll
                for (int j = 0; j < NJ; j++) if (j < k) s2 -= Mx[MIX(i,j)]*Mx[MIX(k,j)];
                Mx[MIX(i,k)] = s2 * linv;
            }
        }
        float y[NJ];
#pragma unroll
        for (int i = 0; i < NJ; i++){
            float s2 = rhs[i];
#pragma unroll
            for (int j = 0; j < NJ; j++) if (j < i) s2 -= Mx[MIX(i,j)]*y[j];
            y[i] = s2 * Mx[MIX(i,i)];
        }
        float z[NJ];
#pragma unroll
        for (int i = NJ-1; i >= 0; i--){
            float s2 = y[i];
#pragma unroll
            for (int j = NJ-1; j >= 0; j--) if (j > i) s2 -= Mx[MIX(j,i)]*z[j];
            z[i] = s2 * Mx[MIX(i,i)];
        }

        float o14[14];
#pragma unroll
        for (int i = 0; i < NJ; i++){
            float qdn = qd[i] + DTF*z[i];
            o14[i]      = q[i] + DTF*qdn;
            o14[NJ + i] = qdn;
        }
        float2* o2 = (float2*)(out + e*14);
#pragma unroll
        for (int i = 0; i < 7; i++){ float2 v; v.x = o14[2*i]; v.y = o14[2*i+1]; o2[i] = v; }
    }
}

extern "C" void kernel_launch(void* const* d_in, const int* in_sizes, int n_in,
                              void* d_out, int out_size, void* d_ws, size_t ws_size,
                              hipStream_t stream) {
    const float* x   = (const float*)d_in[0];
    const float* u   = (const float*)d_in[1];
    const float* ax  = (const float*)d_in[2];
    const float* Rt  = (const float*)d_in[3];
    const float* pt  = (const float*)d_in[4];
    const float* Isp = (const float*)d_in[5];
    float* out = (float*)d_out;
    float* cst = (float*)d_ws;   // NJ*CW floats
    int B = in_sizes[0] / 14;
    hipLaunchKernelGGL(panda_prep, dim3(1), dim3(64), 0, stream, ax, Rt, pt, Isp, cst);
    int grid = (B + 63) / 64;
    hipLaunchKernelGGL(panda_step, dim3(grid), dim3(128), 0, stream,
                       x, u, cst, out, B);
}

// Round 5
// 78.423 us; speedup vs baseline: 1.0567x; 1.0567x over previous
//
#include <hip/hip_runtime.h>
#include <math.h>

#define NJ 7
#define DTF 0.01f
#define GRAVF 9.81f
#define MIX(i,j) ((i)*((i)+1)/2 + (j))
#define MPAD 29   // 28 lower-tri floats padded to 29 (free 2-way bank aliasing)
#define CW 28     // const floats per joint (7 x float4)

// Per-joint constant block at cst + j*CW (16B-aligned):
// [0:9)  Rt (row-major)  [9:12) a  [12:15) p  [15] pad
// [16:22) SA = (A00,A01,A02,A11,A12,A22)  [22:25) h  [25] m  [26:28) pad

__device__ __forceinline__ void cross3(const float* a, const float* b, float* o){
    o[0] = a[1]*b[2] - a[2]*b[1];
    o[1] = a[2]*b[0] - a[0]*b[2];
    o[2] = a[0]*b[1] - a[1]*b[0];
}
__device__ __forceinline__ void mv3(const float* E, const float* x, float* y){
    y[0] = E[0]*x[0] + E[1]*x[1] + E[2]*x[2];
    y[1] = E[3]*x[0] + E[4]*x[1] + E[5]*x[2];
    y[2] = E[6]*x[0] + E[7]*x[1] + E[8]*x[2];
}
__device__ __forceinline__ void mtv3(const float* E, const float* x, float* y){
    y[0] = E[0]*x[0] + E[3]*x[1] + E[6]*x[2];
    y[1] = E[1]*x[0] + E[4]*x[1] + E[7]*x[2];
    y[2] = E[2]*x[0] + E[5]*x[1] + E[8]*x[2];
}
__device__ __forceinline__ void symv(const float* S, const float* x, float* y){
    y[0] = S[0]*x[0] + S[1]*x[1] + S[2]*x[2];
    y[1] = S[1]*x[0] + S[3]*x[1] + S[4]*x[2];
    y[2] = S[2]*x[0] + S[4]*x[1] + S[5]*x[2];
}
__device__ __forceinline__ void mm3(const float* A, const float* B, float* o){
#pragma unroll
    for (int r = 0; r < 3; r++)
#pragma unroll
        for (int c = 0; c < 3; c++)
            o[r*3+c] = A[r*3]*B[c] + A[r*3+1]*B[3+c] + A[r*3+2]*B[6+c];
}
__device__ __forceinline__ void congr(const float* E, const float* X, float* o){
    float t[9];
#pragma unroll
    for (int r = 0; r < 3; r++)
#pragma unroll
        for (int c = 0; c < 3; c++)
            t[r*3+c] = E[r]*X[c] + E[3+r]*X[3+c] + E[6+r]*X[6+c];
    mm3(t, E, o);
}
// E = R(q)^T @ Rt  (Rodrigues; pure VALU — issue is cheap, latency is the enemy)
__device__ __forceinline__ void makeE(const float* a, const float* Rt, float s, float c, float* E){
    float omc = 1.0f - c;
    float RT[9];
    RT[0] = c + omc*a[0]*a[0];       RT[1] =  s*a[2] + omc*a[0]*a[1]; RT[2] = -s*a[1] + omc*a[0]*a[2];
    RT[3] = -s*a[2] + omc*a[1]*a[0]; RT[4] = c + omc*a[1]*a[1];       RT[5] =  s*a[0] + omc*a[1]*a[2];
    RT[6] =  s*a[1] + omc*a[2]*a[0]; RT[7] = -s*a[0] + omc*a[2]*a[1]; RT[8] = c + omc*a[2]*a[2];
    mm3(RT, Rt, E);
}
// Batched per-joint constant fetch: 7 independent float4 loads, one wait.
__device__ __forceinline__ void loadJ(const float* __restrict__ cst, int i,
                                      float* Rt, float* a, float* p,
                                      float* SA, float* h, float& m){
    const float4* cb4 = (const float4*)(cst + i*CW);
    float4 c0=cb4[0], c1=cb4[1], c2=cb4[2], c3=cb4[3], c4=cb4[4], c5=cb4[5], c6=cb4[6];
    Rt[0]=c0.x; Rt[1]=c0.y; Rt[2]=c0.z; Rt[3]=c0.w;
    Rt[4]=c1.x; Rt[5]=c1.y; Rt[6]=c1.z; Rt[7]=c1.w;
    Rt[8]=c2.x; a[0]=c2.y; a[1]=c2.z; a[2]=c2.w;
    p[0]=c3.x; p[1]=c3.y; p[2]=c3.z;
    SA[0]=c4.x; SA[1]=c4.y; SA[2]=c4.z; SA[3]=c4.w;
    SA[4]=c5.x; SA[5]=c5.y; h[0]=c5.z; h[1]=c5.w;
    h[2]=c6.x; m=c6.y;
}
__device__ __forceinline__ void loadI(const float* __restrict__ cst, int i,
                                      float* SA, float* h, float& m){
    const float4* cb4 = (const float4*)(cst + i*CW);
    float4 c4=cb4[4], c5=cb4[5], c6=cb4[6];
    SA[0]=c4.x; SA[1]=c4.y; SA[2]=c4.z; SA[3]=c4.w;
    SA[4]=c5.x; SA[5]=c5.y; h[0]=c5.z; h[1]=c5.w;
    h[2]=c6.x; m=c6.y;
}
__device__ __forceinline__ void loadAP(const float* __restrict__ cst, int i,
                                       float* a, float* p){
    const float4* cb4 = (const float4*)(cst + i*CW);
    float4 c2=cb4[2], c3=cb4[3];
    a[0]=c2.y; a[1]=c2.z; a[2]=c2.w;
    p[0]=c3.x; p[1]=c3.y; p[2]=c3.z;
}

__global__ void panda_prep(const float* __restrict__ g_ax, const float* __restrict__ g_Rt,
                           const float* __restrict__ g_pt, const float* __restrict__ g_I,
                           float* __restrict__ cst)
{
    int i = threadIdx.x;
    if (i >= NJ) return;
    float* o = cst + i*CW;
#pragma unroll
    for (int k = 0; k < 9; k++) o[k] = g_Rt[i*9+k];
    o[9]=g_ax[i*3]; o[10]=g_ax[i*3+1]; o[11]=g_ax[i*3+2];
    o[12]=g_pt[i*3]; o[13]=g_pt[i*3+1]; o[14]=g_pt[i*3+2]; o[15]=0.f;
    const float* I6 = g_I + i*36;
    o[16]=I6[0];  o[17]=I6[1];  o[18]=I6[2];
    o[19]=I6[7];  o[20]=I6[8];  o[21]=I6[14];
    o[22]=I6[16]; o[23]=I6[5];  o[24]=I6[9];
    o[25]=I6[21]; o[26]=0.f; o[27]=0.f;
}

// Block = 128 threads = 2 waves on the SAME 64 batch elements.
// Wave 0: RNEA bias -> rhs; after sync: triangular solves + integrate + store.
// Wave 1: CRBA -> Cholesky factor -> LDS.
__global__ __launch_bounds__(128)
void panda_step(const float* __restrict__ x, const float* __restrict__ u,
                const float* __restrict__ cst, float* __restrict__ out, int B)
{
    __shared__ float s_M[64*MPAD];

    const int role = threadIdx.x >> 6;      // wave-uniform
    const int lane = threadIdx.x & 63;
    const int e    = blockIdx.x*64 + lane;
    const bool act = (e < B);

    const float QL[NJ] = {-2.9671f,-1.8326f,-2.9671f,-3.1416f,-2.9671f,-0.0873f,-2.9671f};
    const float QU[NJ] = { 2.9671f, 1.8326f, 2.9671f, 0.0f,    2.9671f, 3.8223f, 2.9671f};

    float q[NJ], qd[NJ], sn[NJ], cs[NJ];
    if (act){
        float xl[14];
        const float2* x2 = (const float2*)(x + e*14);
#pragma unroll
        for (int i = 0; i < 7; i++){ float2 v = x2[i]; xl[2*i] = v.x; xl[2*i+1] = v.y; }
#pragma unroll
        for (int i = 0; i < NJ; i++){
            q[i]  = fminf(fmaxf(xl[i], QL[i]), QU[i]);
            qd[i] = xl[NJ + i];
            __sincosf(q[i], &sn[i], &cs[i]);
        }
    }

    float rhs[NJ];

    if (act && role == 1){
        // =================== CRBA + Cholesky factor ===================
        float SA[6], hc[3], mc;
        {
            float dm; loadI(cst, 6, SA, hc, dm); mc = dm;
        }
        float Fk[NJ][6];
        float Mx[28];
#pragma unroll
        for (int i = NJ-1; i >= 0; i--){
            float Rt[9], a[3], p[3], SAn[6], hn[3], mn;
            loadJ(cst, i, Rt, a, p, SAn, hn, mn);   // SAn etc = joint i's OWN inertia (unused)
            float SAm[6], hm[3], mm_;
            if (i > 0) loadI(cst, i-1, SAm, hm, mm_); // next frame's body inertia
            // F_i = Ic @ S_i = [A a ; a x h]
            symv(SA, a, &Fk[i][0]);
            Fk[i][3] = a[1]*hc[2] - a[2]*hc[1];
            Fk[i][4] = a[2]*hc[0] - a[0]*hc[2];
            Fk[i][5] = a[0]*hc[1] - a[1]*hc[0];
#pragma unroll
            for (int k = i; k < NJ; k++)
                Mx[MIX(k,i)] = a[0]*Fk[k][0] + a[1]*Fk[k][1] + a[2]*Fk[k][2];
            if (i > 0){
                float E[9]; makeE(a, Rt, sn[i], cs[i], E);
                float Af[9] = {SA[0],SA[1],SA[2], SA[1],SA[3],SA[4], SA[2],SA[4],SA[5]};
                float Ap[9]; congr(E, Af, Ap);
                float hr[3]; mtv3(E, hc, hr);
                float hpd = hr[0]*p[0]+hr[1]*p[1]+hr[2]*p[2];
                float ppd = p[0]*p[0]+p[1]*p[1]+p[2]*p[2];
                float dga = 2.0f*hpd + mc*ppd;
                SA[0] = Ap[0] - 2.0f*p[0]*hr[0] - mc*p[0]*p[0] + dga + SAm[0];
                SA[1] = Ap[1] - p[0]*hr[1] - hr[0]*p[1] - mc*p[0]*p[1] + SAm[1];
                SA[2] = Ap[2] - p[0]*hr[2] - hr[0]*p[2] - mc*p[0]*p[2] + SAm[2];
                SA[3] = Ap[4] - 2.0f*p[1]*hr[1] - mc*p[1]*p[1] + dga + SAm[3];
                SA[4] = Ap[5] - p[1]*hr[2] - hr[1]*p[2] - mc*p[1]*p[2] + SAm[4];
                SA[5] = Ap[8] - 2.0f*p[2]*hr[2] - mc*p[2]*p[2] + dga + SAm[5];
                hc[0] = hr[0] + mc*p[0] + hm[0];
                hc[1] = hr[1] + mc*p[1] + hm[1];
                hc[2] = hr[2] + mc*p[2] + hm[2];
                mc += mm_;
#pragma unroll
                for (int k = i; k < NJ; k++){
                    float tm[3], tf[3], cp[3];
                    mtv3(E, &Fk[k][0], tm); mtv3(E, &Fk[k][3], tf);
                    cross3(p, tf, cp);
                    Fk[k][0]=tm[0]+cp[0]; Fk[k][1]=tm[1]+cp[1]; Fk[k][2]=tm[2]+cp[2];
                    Fk[k][3]=tf[0];       Fk[k][4]=tf[1];       Fk[k][5]=tf[2];
                }
            }
        }
        // ridge + Cholesky factor (diag slots hold 1/L_kk)
#pragma unroll
        for (int i = 0; i < NJ; i++) Mx[MIX(i,i)] += 1e-8f;
#pragma unroll
        for (int k = 0; k < NJ; k++){
            float d = Mx[MIX(k,k)];
#pragma unroll
            for (int j = 0; j < NJ; j++) if (j < k) d -= Mx[MIX(k,j)]*Mx[MIX(k,j)];
            float linv = __builtin_amdgcn_rsqf(d);
            Mx[MIX(k,k)] = linv;
#pragma unroll
            for (int i2 = k+1; i2 < NJ; i2++){
                float s2 = Mx[MIX(i2,k)];
#pragma unroll
                for (int j = 0; j < NJ; j++) if (j < k) s2 -= Mx[MIX(i2,j)]*Mx[MIX(k,j)];
                Mx[MIX(i2,k)] = s2 * linv;
            }
        }
#pragma unroll
        for (int j = 0; j < 28; j++) s_M[lane*MPAD + j] = Mx[j];
    }
    else if (act){
        // =================== RNEA: bias forces ===================
#pragma unroll
        for (int i = 0; i < NJ; i++) rhs[i] = u[e*NJ + i];
        float Earr[NJ][9];
        float FF[NJ][6];
        float w[3]  = {0.f,0.f,0.f}, vl[3] = {0.f,0.f,0.f};
        float aw[3] = {0.f,0.f,0.f}, av[3] = {0.f,0.f,GRAVF};
#pragma unroll
        for (int i = 0; i < NJ; i++){
            float Rt[9], a[3], p[3], SAi[6], hi[3], mi;
            loadJ(cst, i, Rt, a, p, SAi, hi, mi);
            float* E = &Earr[i][0];
            makeE(a, Rt, sn[i], cs[i], E);
            float qdi = qd[i];
            float tw[3]; mv3(E, w, tw);
            float nw[3] = { tw[0]+a[0]*qdi, tw[1]+a[1]*qdi, tw[2]+a[2]*qdi };
            float cwp[3]; cross3(w, p, cwp);
            float t1[3] = { vl[0]+cwp[0], vl[1]+cwp[1], vl[2]+cwp[2] };
            float nvl[3]; mv3(E, t1, nvl);
            float taw[3]; mv3(E, aw, taw);
            float cna[3]; cross3(nw, a, cna);
            float naw[3] = { taw[0]+qdi*cna[0], taw[1]+qdi*cna[1], taw[2]+qdi*cna[2] };
            float cap[3]; cross3(aw, p, cap);
            float t2[3] = { av[0]+cap[0], av[1]+cap[1], av[2]+cap[2] };
            float tav[3]; mv3(E, t2, tav);
            float cva[3]; cross3(nvl, a, cva);
            float nav[3] = { tav[0]+qdi*cva[0], tav[1]+qdi*cva[1], tav[2]+qdi*cva[2] };
            float Ivt[3], Iat[3], hxv[3], hxa[3];
            symv(SAi, nw, Ivt);  cross3(hi, nvl, hxv);
            symv(SAi, naw, Iat); cross3(hi, nav, hxa);
#pragma unroll
            for (int k = 0; k < 3; k++){ Ivt[k] += hxv[k]; Iat[k] += hxa[k]; }
            float hxw[3], hxaw[3];
            cross3(hi, nw, hxw); cross3(hi, naw, hxaw);
            float Ivb[3] = { mi*nvl[0]-hxw[0], mi*nvl[1]-hxw[1], mi*nvl[2]-hxw[2] };
            float Iab[3] = { mi*nav[0]-hxaw[0], mi*nav[1]-hxaw[1], mi*nav[2]-hxaw[2] };
            float c1[3], c2[3], c3[3];
            cross3(nw, Ivt, c1); cross3(nvl, Ivb, c2); cross3(nw, Ivb, c3);
            FF[i][0] = Iat[0]+c1[0]+c2[0];
            FF[i][1] = Iat[1]+c1[1]+c2[1];
            FF[i][2] = Iat[2]+c1[2]+c2[2];
            FF[i][3] = Iab[0]+c3[0];
            FF[i][4] = Iab[1]+c3[1];
            FF[i][5] = Iab[2]+c3[2];
#pragma unroll
            for (int k = 0; k < 3; k++){ w[k]=nw[k]; vl[k]=nvl[k]; aw[k]=naw[k]; av[k]=nav[k]; }
        }
        // backward fold (E reused from registers; only a,p reloaded — 2 loads/joint)
#pragma unroll
        for (int i = NJ-1; i >= 0; i--){
            float a[3], p[3];
            loadAP(cst, i, a, p);
            rhs[i] -= a[0]*FF[i][0] + a[1]*FF[i][1] + a[2]*FF[i][2];
            if (i > 0){
                const float* E = &Earr[i][0];
                float tm[3], tf[3], cp[3];
                mtv3(E, &FF[i][0], tm); mtv3(E, &FF[i][3], tf);
                cross3(p, tf, cp);
                FF[i-1][0]+=tm[0]+cp[0]; FF[i-1][1]+=tm[1]+cp[1]; FF[i-1][2]+=tm[2]+cp[2];
                FF[i-1][3]+=tf[0];       FF[i-1][4]+=tf[1];       FF[i-1][5]+=tf[2];
            }
        }
    }

    __syncthreads();

    if (act && role == 0){
        // =================== triangular solves + integrate ===================
        float Mx[28];
#pragma unroll
        for (int j = 0; j < 28; j++) Mx[j] = s_M[lane*MPAD + j];
        float y[NJ];
#pragma unroll
        for (int i = 0; i < NJ; i++){
            float s2 = rhs[i];
#pragma unroll
            for (int j = 0; j < NJ; j++) if (j < i) s2 -= Mx[MIX(i,j)]*y[j];
            y[i] = s2 * Mx[MIX(i,i)];
        }
        float z[NJ];
#pragma unroll
        for (int i = NJ-1; i >= 0; i--){
            float s2 = y[i];
#pragma unroll
            for (int j = NJ-1; j >= 0; j--) if (j > i) s2 -= Mx[MIX(j,i)]*z[j];
            z[i] = s2 * Mx[MIX(i,i)];
        }
        float o14[14];
#pragma unroll
        for (int i = 0; i < NJ; i++){
            float qdn = qd[i] + DTF*z[i];
            o14[i]      = q[i] + DTF*qdn;
            o14[NJ + i] = qdn;
        }
        float2* o2 = (float2*)(out + e*14);
#pragma unroll
        for (int i = 0; i < 7; i++){ float2 v; v.x = o14[2*i]; v.y = o14[2*i+1]; o2[i] = v; }
    }
}

extern "C" void kernel_launch(void* const* d_in, const int* in_sizes, int n_in,
                              void* d_out, int out_size, void* d_ws, size_t ws_size,
                              hipStream_t stream) {
    const float* x   = (const float*)d_in[0];
    const float* u   = (const float*)d_in[1];
    const float* ax  = (const float*)d_in[2];
    const float* Rt  = (const float*)d_in[3];
    const float* pt  = (const float*)d_in[4];
    const float* Isp = (const float*)d_in[5];
    float* out = (float*)d_out;
    float* cst = (float*)d_ws;   // NJ*CW floats
    int B = in_sizes[0] / 14;
    hipLaunchKernelGGL(panda_prep, dim3(1), dim3(64), 0, stream, ax, Rt, pt, Isp, cst);
    int grid = (B + 63) / 64;
    hipLaunchKernelGGL(panda_step, dim3(grid), dim3(128), 0, stream,
                       x, u, cst, out, B);
}